// Round 6
// baseline (885.888 us; speedup 1.0000x reference)
//
#include <hip/hip_runtime.h>
#include <stdint.h>

#define EMB 1024
#define LROW 40   // attn-kernel LDS pitch (u16)

typedef unsigned short u16;
typedef __attribute__((ext_vector_type(8))) unsigned short u16x8;
typedef __attribute__((ext_vector_type(8))) __bf16 bf16x8;
typedef __attribute__((ext_vector_type(4))) float f32x4;

__device__ __forceinline__ u16 f2bf(float f) {
  union { float f; uint32_t u; } x; x.f = f;
  uint32_t u = x.u;
  u += 0x7fff + ((u >> 16) & 1u);   // round-to-nearest-even
  return (u16)(u >> 16);
}

// 8x f32 -> bf16x8 via native casts (v_cvt_pk_bf16_f32).
__device__ __forceinline__ bf16x8 cvt8(float4 a, float4 b) {
  bf16x8 r;
  r[0] = (__bf16)a.x; r[1] = (__bf16)a.y; r[2] = (__bf16)a.z; r[3] = (__bf16)a.w;
  r[4] = (__bf16)b.x; r[5] = (__bf16)b.y; r[6] = (__bf16)b.z; r[7] = (__bf16)b.w;
  return r;
}

// Async global->LDS, 16B per lane. LDS dest is wave-uniform base + lane*16.
__device__ __forceinline__ void gl16(const u16* g, u16* l) {
  __builtin_amdgcn_global_load_lds(
      (const __attribute__((address_space(1))) void*)g,
      (__attribute__((address_space(3))) void*)l, 16, 0, 0);
}

// XCD-chunked block swizzle (m157; requires nwg % 8 == 0 -- 1536/512 both ok).
__device__ __forceinline__ int xcd_logical(int orig, int nwg) {
  return (orig & 7) * (nwg >> 3) + (orig >> 3);
}

// ---------------------------------------------------------------------------
// Weight cvt: y-indexed (src,dst) pairs, each exactly EMB*EMB elements.
// ---------------------------------------------------------------------------
__global__ __launch_bounds__(256) void cvtw_kernel(
    const float* __restrict__ s0, u16* __restrict__ d0,
    const float* __restrict__ s1, u16* __restrict__ d1,
    const float* __restrict__ s2, u16* __restrict__ d2,
    const float* __restrict__ s3, u16* __restrict__ d3)
{
  const float* s; u16* d;
  switch (blockIdx.y) {
    case 0:  s = s0; d = d0; break;
    case 1:  s = s1; d = d1; break;
    case 2:  s = s2; d = d2; break;
    default: s = s3; d = d3; break;
  }
  const size_t i = (size_t)blockIdx.x * 256 + threadIdx.x;
  const float4* f = (const float4*)(s + i * 8);
  const float4 lo = f[0], hi = f[1];
  *(bf16x8*)(d + i * 8) = cvt8(lo, hi);
}

// ---------------------------------------------------------------------------
// Fused QKV projection. Round-6 changes vs round 5 (which was perf-neutral):
//  * __launch_bounds__(256,5): LDS 32KB/block -> 5 blocks/CU fit exactly;
//    occupancy 10 -> 20 waves/CU (the all-pipes-idle signature says latency).
//  * K-phase stagger: block starts its K-loop at ((by*3+z*21)&31)*32. Blocks
//    sharing an X panel (same by,z; all bx) keep the SAME phase (L2 reuse
//    intact); different by-groups desynchronize -> breaks the convoy where
//    every resident wave stalls on the same K-slice fetch at the same time.
//  * dbuf + single barrier + counted vmcnt(4) kept from round 5.
// ---------------------------------------------------------------------------
__global__ __launch_bounds__(256, 5) void qkv_fused_kernel(
    const float* __restrict__ Vx, const float* __restrict__ Kx,
    const float* __restrict__ Qx, const u16* __restrict__ Wb,
    const float* __restrict__ Bv, const float* __restrict__ Bk,
    const float* __restrict__ Bq,
    u16* __restrict__ cv, u16* __restrict__ ck, u16* __restrict__ cq,
    int N, int K, int M)
{
  __shared__ __attribute__((aligned(16))) u16 Al[2][128 * 32];
  __shared__ __attribute__((aligned(16))) u16 Bl[2][128 * 32];

  const int nwg = (N >> 7) * (M >> 7) * 3;
  const int logical = xcd_logical(blockIdx.x, nwg);
  const int per_z = (N >> 7) * (M >> 7);
  const int z = logical / per_z;
  const int rem = logical - z * per_z;
  const int nbx = N >> 7;
  const int by = rem / nbx, bx = rem - by * nbx;

  const float* X; const u16* W; const float* Bias; u16* C;
  switch (z) {
    case 0:  X = Vx; W = Wb;                   Bias = Bv; C = cv; break;
    case 1:  X = Kx; W = Wb + EMB * EMB;       Bias = Bk; C = ck; break;
    default: X = Qx; W = Wb + 2 * EMB * EMB;   Bias = Bq; C = cq; break;
  }

  const int tid  = threadIdx.x;
  const int lane = tid & 63;
  const int w    = tid >> 6;
  const int wm = w >> 1, wn = w & 1;
  const int r16 = lane & 15, quad = lane >> 4;
  const int bm = by * 128, bn = bx * 128;

  const int NSTEP = K >> 5;            // 32 K-steps (K=1024)
  const int SM = NSTEP - 1;            // step mask (pow2)
  const int ph = (by * 3 + z * 21) & SM;   // per-panel-group phase

  // A staging (reg -> swizzled ds_write)
  const int s0 = tid, s1 = tid + 256;
  const int r0 = s0 >> 2, c0 = s0 & 3;
  const int r1 = s1 >> 2, c1 = s1 & 3;
  const int lA0 = r0 * 32 + ((c0 ^ ((r0 >> 1) & 3)) * 8);
  const int lA1 = r1 * 32 + ((c1 ^ ((r1 >> 1) & 3)) * 8);
  const size_t xo0 = (size_t)(bm + r0) * K + c0 * 8;
  const size_t xo1 = (size_t)(bm + r1) * K + c1 * 8;

  // B staging (gl16, linear dest, pre-swizzled source)
  const int bs0 = w * 64 + lane, bs1 = bs0 + 256;
  const int br0 = bs0 >> 2, bc0 = ((bs0 & 3) ^ ((br0 >> 1) & 3)) * 8;
  const int br1 = bs1 >> 2, bc1 = ((bs1 & 3) ^ ((br1 >> 1) & 3)) * 8;
  const u16* srcB0 = W + (size_t)(bn + br0) * K + bc0;
  const u16* srcB1 = W + (size_t)(bn + br1) * K + bc1;
  const int dB0o = (w * 64) * 8, dB1o = dB0o + 256 * 8;

  // frag reads
  const int swz = (quad ^ ((r16 >> 1) & 3)) * 8;
  int offA[4], offB[4];
#pragma unroll
  for (int t = 0; t < 4; t++) {
    offA[t] = (wm * 64 + t * 16 + r16) * 32 + swz;
    offB[t] = (wn * 64 + t * 16 + r16) * 32 + swz;
  }

  f32x4 acc[4][4];
#pragma unroll
  for (int i = 0; i < 4; i++)
#pragma unroll
    for (int j = 0; j < 4; j++)
      acc[i][j] = f32x4{0.f, 0.f, 0.f, 0.f};

  // ---- prologue: step it=0 (k = ph*32) -> buf0; X for it=1 -> regs
  const int kP0 = ph << 5;
  const int kP1 = ((ph + 1) & SM) << 5;
  float4 xa0 = *(const float4*)(X + xo0 + kP0), xa1 = *(const float4*)(X + xo0 + kP0 + 4);
  float4 xb0 = *(const float4*)(X + xo1 + kP0), xb1 = *(const float4*)(X + xo1 + kP0 + 4);
  *(bf16x8*)&Al[0][lA0] = cvt8(xa0, xa1);
  *(bf16x8*)&Al[0][lA1] = cvt8(xb0, xb1);
  gl16(srcB0 + kP0, &Bl[0][dB0o]);
  gl16(srcB1 + kP0, &Bl[0][dB1o]);
  __builtin_amdgcn_sched_barrier(0);
  xa0 = *(const float4*)(X + xo0 + kP1); xa1 = *(const float4*)(X + xo0 + kP1 + 4);
  xb0 = *(const float4*)(X + xo1 + kP1); xb1 = *(const float4*)(X + xo1 + kP1 + 4);
  asm volatile("s_waitcnt vmcnt(4) lgkmcnt(0)\n\ts_barrier" ::: "memory");

  for (int it = 0; it < NSTEP; ++it) {
    const int cur = it & 1, nxt = cur ^ 1;
    const int kn  = ((it + 1 + ph) & SM) << 5;   // k of step it+1
    const int kn2 = ((it + 2 + ph) & SM) << 5;   // k of step it+2 (wraps: valid)

    // stage step it+1 into buf[nxt] (regs hold its X data)
    *(bf16x8*)&Al[nxt][lA0] = cvt8(xa0, xa1);
    *(bf16x8*)&Al[nxt][lA1] = cvt8(xb0, xb1);
    gl16(srcB0 + kn, &Bl[nxt][dB0o]);
    gl16(srcB1 + kn, &Bl[nxt][dB1o]);
    __builtin_amdgcn_sched_barrier(0);   // pin: gl16 issued BEFORE X loads
    xa0 = *(const float4*)(X + xo0 + kn2); xa1 = *(const float4*)(X + xo0 + kn2 + 4);
    xb0 = *(const float4*)(X + xo1 + kn2); xb1 = *(const float4*)(X + xo1 + kn2 + 4);

    bf16x8 a[4], b[4];
#pragma unroll
    for (int t = 0; t < 4; t++) a[t] = *(const bf16x8*)&Al[cur][offA[t]];
#pragma unroll
    for (int t = 0; t < 4; t++) b[t] = *(const bf16x8*)&Bl[cur][offB[t]];
    asm volatile("s_waitcnt lgkmcnt(0)" ::: "memory");
    __builtin_amdgcn_sched_barrier(0);   // rule #18: no MFMA hoist past wait

#pragma unroll
    for (int tm = 0; tm < 4; tm++)
#pragma unroll
      for (int tn = 0; tn < 4; tn++)
        acc[tm][tn] = __builtin_amdgcn_mfma_f32_16x16x32_bf16(a[tm], b[tn], acc[tm][tn], 0, 0, 0);

    // counted drain: 4 newest vmem = X(it+2) loads stay in flight; the 2
    // gl16 into buf[nxt] (older) are proven complete. One barrier per iter.
    asm volatile("s_waitcnt vmcnt(4)\n\ts_barrier" ::: "memory");
  }

  // C/D layout: col = lane&15, row = quad*4 + reg (verified m89/m91)
#pragma unroll
  for (int tn = 0; tn < 4; tn++) {
    const int col = bn + wn * 64 + tn * 16 + r16;
    const float bias = Bias[col];
#pragma unroll
    for (int tm = 0; tm < 4; tm++) {
      const int row0 = bm + wm * 64 + tm * 16 + quad * 4;
#pragma unroll
      for (int r = 0; r < 4; r++)
        C[(size_t)(row0 + r) * N + col] = f2bf(acc[tm][tn][r] + bias);
    }
  }
}

// ---------------------------------------------------------------------------
// Out projection: X bf16, W bf16, C f32. Same occupancy bump (5 blocks/CU)
// + K-phase stagger (by-keyed). dbuf, one barrier + vmcnt(0) per iter (its 4
// gl16 are the newest ops -- counting needs a 3-ring, deliberately not done:
// round-5 showed counted-vs-drain is not the lever in 2-phase).
// ---------------------------------------------------------------------------
__global__ __launch_bounds__(256, 5) void out_gemm_kernel(
    const u16* __restrict__ X, const u16* __restrict__ W,
    const float* __restrict__ Bias, float* __restrict__ C, int N, int K, int M)
{
  __shared__ __attribute__((aligned(16))) u16 Al[2][128 * 32];
  __shared__ __attribute__((aligned(16))) u16 Bl[2][128 * 32];

  const int nwg = (N >> 7) * (M >> 7);
  const int logical = xcd_logical(blockIdx.x, nwg);
  const int nbx = N >> 7;
  const int by = logical / nbx, bx = logical - by * nbx;

  const int tid  = threadIdx.x;
  const int lane = tid & 63;
  const int w    = tid >> 6;
  const int wm = w >> 1, wn = w & 1;
  const int r16 = lane & 15, quad = lane >> 4;
  const int bm = by * 128, bn = bx * 128;

  const int NSTEP = K >> 5;
  const int SM = NSTEP - 1;
  const int ph = (by * 3) & SM;

  const int s0 = w * 64 + lane, s1 = s0 + 256;
  const int r0 = s0 >> 2, c0 = ((s0 & 3) ^ ((r0 >> 1) & 3)) * 8;
  const int r1 = s1 >> 2, c1 = ((s1 & 3) ^ ((r1 >> 1) & 3)) * 8;

  const u16* srcA0 = X + (size_t)(bm + r0) * K + c0;
  const u16* srcA1 = X + (size_t)(bm + r1) * K + c1;
  const u16* srcB0 = W + (size_t)(bn + r0) * K + c0;
  const u16* srcB1 = W + (size_t)(bn + r1) * K + c1;

  const int dA0o = (w * 64) * 8, dA1o = dA0o + 256 * 8;

  const int swz = (quad ^ ((r16 >> 1) & 3)) * 8;
  int offA[4], offB[4];
#pragma unroll
  for (int t = 0; t < 4; t++) {
    offA[t] = (wm * 64 + t * 16 + r16) * 32 + swz;
    offB[t] = (wn * 64 + t * 16 + r16) * 32 + swz;
  }

  f32x4 acc[4][4];
#pragma unroll
  for (int i = 0; i < 4; i++)
#pragma unroll
    for (int j = 0; j < 4; j++)
      acc[i][j] = f32x4{0.f, 0.f, 0.f, 0.f};

  // prologue: step 0 (k = ph*32) -> buf0
  const int kP0 = ph << 5;
  gl16(srcA0 + kP0, &Al[0][dA0o]);
  gl16(srcA1 + kP0, &Al[0][dA1o]);
  gl16(srcB0 + kP0, &Bl[0][dA0o]);
  gl16(srcB1 + kP0, &Bl[0][dA1o]);
  asm volatile("s_waitcnt vmcnt(0)\n\ts_barrier" ::: "memory");

  for (int it = 0; it < NSTEP; ++it) {
    const int cur = it & 1, nxt = cur ^ 1;
    const int kn = ((it + 1 + ph) & SM) << 5;

    gl16(srcA0 + kn, &Al[nxt][dA0o]);
    gl16(srcA1 + kn, &Al[nxt][dA1o]);
    gl16(srcB0 + kn, &Bl[nxt][dA0o]);
    gl16(srcB1 + kn, &Bl[nxt][dA1o]);

    bf16x8 a[4], b[4];
#pragma unroll
    for (int t = 0; t < 4; t++) a[t] = *(const bf16x8*)&Al[cur][offA[t]];
#pragma unroll
    for (int t = 0; t < 4; t++) b[t] = *(const bf16x8*)&Bl[cur][offB[t]];
    asm volatile("s_waitcnt lgkmcnt(0)" ::: "memory");
    __builtin_amdgcn_sched_barrier(0);

#pragma unroll
    for (int tm = 0; tm < 4; tm++)
#pragma unroll
      for (int tn = 0; tn < 4; tn++)
        acc[tm][tn] = __builtin_amdgcn_mfma_f32_16x16x32_bf16(a[tm], b[tn], acc[tm][tn], 0, 0, 0);

    asm volatile("s_waitcnt vmcnt(0)\n\ts_barrier" ::: "memory");
  }

#pragma unroll
  for (int tn = 0; tn < 4; tn++) {
    const int col = bn + wn * 64 + tn * 16 + r16;
    const float bias = Bias[col];
#pragma unroll
    for (int tm = 0; tm < 4; tm++) {
      const int row0 = bm + wm * 64 + tm * 16 + quad * 4;
#pragma unroll
      for (int r = 0; r < 4; r++)
        C[(size_t)(row0 + r) * N + col] = acc[tm][tn][r] + bias;
    }
  }
}

// ---------------------------------------------------------------------------
// Per-token head-mixing attention (logic unchanged; occupancy 4 -> 6/CU,
// LDS 25.6KB*6 = 154KB fits; VGPR cap 85 is ample).
// ---------------------------------------------------------------------------
__global__ __launch_bounds__(256, 6) void attn_heads_kernel(
    const u16* Q, const u16* Km, const u16* V, u16* O)
{
  __shared__ __attribute__((aligned(16))) u16 P[4][16 * LROW];
  __shared__ __attribute__((aligned(16))) u16 VT[4][64 * LROW];

  const int tid = threadIdx.x, lane = tid & 63, w = tid >> 6;
  const int r16 = lane & 15, quad = lane >> 4;
  const size_t base = ((size_t)blockIdx.x * 4 + w) * EMB;

  const bf16x8 aq0 = *(const bf16x8*)&Q[base + r16 * 64 + quad * 8];
  const bf16x8 aq1 = *(const bf16x8*)&Q[base + r16 * 64 + 32 + quad * 8];
  const bf16x8 bk0 = *(const bf16x8*)&Km[base + r16 * 64 + quad * 8];
  const bf16x8 bk1 = *(const bf16x8*)&Km[base + r16 * 64 + 32 + quad * 8];

  const u16x8 v0 = *(const u16x8*)&V[base + lane * 16];
  const u16x8 v1 = *(const u16x8*)&V[base + lane * 16 + 8];
  const u16x8 z8 = {0, 0, 0, 0, 0, 0, 0, 0};
  *(u16x8*)&VT[w][lane * LROW + 16] = z8;
  *(u16x8*)&VT[w][lane * LROW + 24] = z8;
  const int g = lane >> 2, dbase = (lane & 3) * 16;
#pragma unroll
  for (int i = 0; i < 8; i++) {
    VT[w][(dbase + i) * LROW + g]     = v0[i];
    VT[w][(dbase + 8 + i) * LROW + g] = v1[i];
  }

  f32x4 s = f32x4{0.f, 0.f, 0.f, 0.f};
  s = __builtin_amdgcn_mfma_f32_16x16x32_bf16(aq0, bk0, s, 0, 0, 0);
  s = __builtin_amdgcn_mfma_f32_16x16x32_bf16(aq1, bk1, s, 0, 0, 0);

  float p[4];
#pragma unroll
  for (int r = 0; r < 4; r++) {
    float v = s[r] * 0.125f;
    float m = v;
#pragma unroll
    for (int d = 8; d; d >>= 1) m = fmaxf(m, __shfl_xor(m, d, 16));
    float e = __expf(v - m);
    float sum = e;
#pragma unroll
    for (int d = 8; d; d >>= 1) sum += __shfl_xor(sum, d, 16);
    p[r] = e / sum;
  }

#pragma unroll
  for (int r = 0; r < 4; r++) {
    P[w][(quad * 4 + r) * LROW + r16]      = f2bf(p[r]);
    P[w][(quad * 4 + r) * LROW + 16 + r16] = 0;
  }
  __syncthreads();

  const bf16x8 pa = *(const bf16x8*)&P[w][r16 * LROW + quad * 8];

#pragma unroll
  for (int c = 0; c < 4; c++) {
    const bf16x8 bvv = *(const bf16x8*)&VT[w][(c * 16 + r16) * LROW + quad * 8];
    f32x4 o = f32x4{0.f, 0.f, 0.f, 0.f};
    o = __builtin_amdgcn_mfma_f32_16x16x32_bf16(pa, bvv, o, 0, 0, 0);
#pragma unroll
    for (int r = 0; r < 4; r++)
      O[base + (size_t)(quad * 4 + r) * 64 + c * 16 + r16] = f2bf(o[r]);
  }
}

// ---------------------------------------------------------------------------
// Orchestration (unchanged).
// ---------------------------------------------------------------------------
extern "C" void kernel_launch(void* const* d_in, const int* in_sizes, int n_in,
                              void* d_out, int out_size, void* d_ws, size_t ws_size,
                              hipStream_t stream)
{
  const float* values = (const float*)d_in[0];
  const float* keys   = (const float*)d_in[1];
  const float* query  = (const float*)d_in[2];
  const float* Wv = (const float*)d_in[3];
  const float* bv = (const float*)d_in[4];
  const float* Wk = (const float*)d_in[5];
  const float* bk = (const float*)d_in[6];
  const float* Wq = (const float*)d_in[7];
  const float* bq = (const float*)d_in[8];
  const float* Wo = (const float*)d_in[9];
  const float* bo = (const float*)d_in[10];

  const int M = in_sizes[0] / EMB;   // 8192 tokens
  const int N = EMB, K = EMB;

  u16* q    = (u16*)d_ws;
  u16* kbuf = q + (size_t)M * EMB;
  u16* v    = (u16*)d_out;
  u16* wb   = v + (size_t)M * EMB;
  u16* ao   = q;

  const size_t base_ws = (size_t)2 * M * EMB * sizeof(u16);
  const bool wo_in_ws = ws_size >= base_ws + (size_t)EMB * EMB * sizeof(u16);
  u16* wob = wo_in_ws ? kbuf + (size_t)M * EMB : kbuf;

  dim3 blk(256, 1, 1);
  dim3 cwg(EMB * EMB / 8 / 256, wo_in_ws ? 4 : 3, 1);

  hipLaunchKernelGGL(cvtw_kernel, cwg, blk, 0, stream,
                     Wv, wb, Wk, wb + EMB * EMB, Wq, wb + 2 * EMB * EMB, Wo, wob);
  hipLaunchKernelGGL(qkv_fused_kernel, dim3((N / 128) * (M / 128) * 3, 1, 1), blk, 0, stream,
                     values, keys, query, wb, bv, bk, bq, v, kbuf, q, N, K, M);
  hipLaunchKernelGGL(attn_heads_kernel, dim3(M / 4, 1, 1), blk, 0, stream,
                     q, kbuf, v, ao);
  if (!wo_in_ws)
    hipLaunchKernelGGL(cvtw_kernel, dim3(EMB * EMB / 8 / 256, 1, 1), blk, 0, stream,
                       Wo, wob, (const float*)nullptr, (u16*)nullptr,
                       (const float*)nullptr, (u16*)nullptr,
                       (const float*)nullptr, (u16*)nullptr);
  hipLaunchKernelGGL(out_gemm_kernel, dim3((N / 128) * (M / 128), 1, 1), blk, 0, stream,
                     ao, wob, bo, (float*)d_out, N, K, M);
}

// Round 7
// 270.101 us; speedup vs baseline: 3.2798x; 3.2798x over previous
//
#include <hip/hip_runtime.h>
#include <stdint.h>

#define EMB 1024
#define LROW 40   // attn-kernel LDS pitch (u16)

typedef unsigned short u16;
typedef __attribute__((ext_vector_type(8))) unsigned short u16x8;
typedef __attribute__((ext_vector_type(8))) __bf16 bf16x8;
typedef __attribute__((ext_vector_type(4))) float f32x4;

__device__ __forceinline__ u16 f2bf(float f) {
  union { float f; uint32_t u; } x; x.f = f;
  uint32_t u = x.u;
  u += 0x7fff + ((u >> 16) & 1u);   // round-to-nearest-even
  return (u16)(u >> 16);
}

// 8x f32 -> bf16x8 via native casts (v_cvt_pk_bf16_f32).
__device__ __forceinline__ bf16x8 cvt8(float4 a, float4 b) {
  bf16x8 r;
  r[0] = (__bf16)a.x; r[1] = (__bf16)a.y; r[2] = (__bf16)a.z; r[3] = (__bf16)a.w;
  r[4] = (__bf16)b.x; r[5] = (__bf16)b.y; r[6] = (__bf16)b.z; r[7] = (__bf16)b.w;
  return r;
}

// Async global->LDS, 16B per lane. LDS dest is wave-uniform base + lane*16.
__device__ __forceinline__ void gl16(const u16* g, u16* l) {
  __builtin_amdgcn_global_load_lds(
      (const __attribute__((address_space(1))) void*)g,
      (__attribute__((address_space(3))) void*)l, 16, 0, 0);
}

// XCD-chunked block swizzle (m157; requires nwg % 8 == 0 -- 1536/512 both ok).
__device__ __forceinline__ int xcd_logical(int orig, int nwg) {
  return (orig & 7) * (nwg >> 3) + (orig >> 3);
}

// ---------------------------------------------------------------------------
// Weight cvt: y-indexed (src,dst) pairs, each exactly EMB*EMB elements.
// ---------------------------------------------------------------------------
__global__ __launch_bounds__(256) void cvtw_kernel(
    const float* __restrict__ s0, u16* __restrict__ d0,
    const float* __restrict__ s1, u16* __restrict__ d1,
    const float* __restrict__ s2, u16* __restrict__ d2,
    const float* __restrict__ s3, u16* __restrict__ d3)
{
  const float* s; u16* d;
  switch (blockIdx.y) {
    case 0:  s = s0; d = d0; break;
    case 1:  s = s1; d = d1; break;
    case 2:  s = s2; d = d2; break;
    default: s = s3; d = d3; break;
  }
  const size_t i = (size_t)blockIdx.x * 256 + threadIdx.x;
  const float4* f = (const float4*)(s + i * 8);
  const float4 lo = f[0], hi = f[1];
  *(bf16x8*)(d + i * 8) = cvt8(lo, hi);
}

// ---------------------------------------------------------------------------
// Fused QKV projection. Round-7: depth-2 W pipeline via 3-slot LDS ring.
//   * B(W) staged 2 tiles AHEAD (gl16 for tile it+2 at iter it) into a ring
//     of 3 buffers -> each gl16 has a FULL iteration to complete (round-5's
//     schedule drained them at the same-iter barrier: zero window; that
//     serial L2 latency was the ~125us plateau).
//   * A-path: X f32 prefetched 2 ahead into regs (as before); the cvt's
//     compiler-inserted vmcnt drains exactly {B(it+1), X(it+1)} -- both one
//     iteration old -- keeping B(it+2) in flight.
//   * End-of-iter: vmcnt(6) keeps the 6 newest (B(it+2)x2 + X(it+2)x4).
//     B(it+1) completion before the barrier is established at the cvt wait.
//   * Race ledger: ring slot written at iter it was last READ at iter it-1;
//     those ds_reads are lgkmcnt(0)-drained before the it-1 barrier, and the
//     write is after that barrier -> no WAR race. One barrier per iter.
//   * launch_bounds(256,3): 170-reg cap (round-6 lesson: (256,5)'s 102-cap
//     spilled acc to scratch -> 1.4 GB writes). LDS 40KB -> 4 blocks/CU.
// ---------------------------------------------------------------------------
__global__ __launch_bounds__(256, 3) void qkv_fused_kernel(
    const float* __restrict__ Vx, const float* __restrict__ Kx,
    const float* __restrict__ Qx, const u16* __restrict__ Wb,
    const float* __restrict__ Bv, const float* __restrict__ Bk,
    const float* __restrict__ Bq,
    u16* __restrict__ cv, u16* __restrict__ ck, u16* __restrict__ cq,
    int N, int K, int M)
{
  __shared__ __attribute__((aligned(16))) u16 Al[2][128 * 32];
  __shared__ __attribute__((aligned(16))) u16 Bl[3][128 * 32];

  const int nwg = (N >> 7) * (M >> 7) * 3;
  const int logical = xcd_logical(blockIdx.x, nwg);
  const int per_z = (N >> 7) * (M >> 7);
  const int z = logical / per_z;
  const int rem = logical - z * per_z;
  const int nbx = N >> 7;
  const int by = rem / nbx, bx = rem - by * nbx;

  const float* X; const u16* W; const float* Bias; u16* C;
  switch (z) {
    case 0:  X = Vx; W = Wb;                   Bias = Bv; C = cv; break;
    case 1:  X = Kx; W = Wb + EMB * EMB;       Bias = Bk; C = ck; break;
    default: X = Qx; W = Wb + 2 * EMB * EMB;   Bias = Bq; C = cq; break;
  }

  const int tid  = threadIdx.x;
  const int lane = tid & 63;
  const int w    = tid >> 6;
  const int wm = w >> 1, wn = w & 1;
  const int r16 = lane & 15, quad = lane >> 4;
  const int bm = by * 128, bn = bx * 128;

  const int NSTEP = K >> 5;   // 32
  const int SM = NSTEP - 1;

  // A staging (reg -> swizzled ds_write)
  const int s0 = tid, s1 = tid + 256;
  const int r0 = s0 >> 2, c0 = s0 & 3;
  const int r1 = s1 >> 2, c1 = s1 & 3;
  const int lA0 = r0 * 32 + ((c0 ^ ((r0 >> 1) & 3)) * 8);
  const int lA1 = r1 * 32 + ((c1 ^ ((r1 >> 1) & 3)) * 8);
  const size_t xo0 = (size_t)(bm + r0) * K + c0 * 8;
  const size_t xo1 = (size_t)(bm + r1) * K + c1 * 8;

  // B staging (gl16, linear dest, pre-swizzled source)
  const int bs0 = w * 64 + lane, bs1 = bs0 + 256;
  const int br0 = bs0 >> 2, bc0 = ((bs0 & 3) ^ ((br0 >> 1) & 3)) * 8;
  const int br1 = bs1 >> 2, bc1 = ((bs1 & 3) ^ ((br1 >> 1) & 3)) * 8;
  const u16* srcB0 = W + (size_t)(bn + br0) * K + bc0;
  const u16* srcB1 = W + (size_t)(bn + br1) * K + bc1;
  const int dB0o = (w * 64) * 8, dB1o = dB0o + 256 * 8;

  // frag reads
  const int swz = (quad ^ ((r16 >> 1) & 3)) * 8;
  int offA[4], offB[4];
#pragma unroll
  for (int t = 0; t < 4; t++) {
    offA[t] = (wm * 64 + t * 16 + r16) * 32 + swz;
    offB[t] = (wn * 64 + t * 16 + r16) * 32 + swz;
  }

  f32x4 acc[4][4];
#pragma unroll
  for (int i = 0; i < 4; i++)
#pragma unroll
    for (int j = 0; j < 4; j++)
      acc[i][j] = f32x4{0.f, 0.f, 0.f, 0.f};

  // ---- prologue ----
  // issue order: X0(4) [oldest], B0(2), B1(2); cvt waits vmcnt(4) -> X0 only;
  // then X1(4); final vmcnt(6) drains B0 (oldest 2), keeps B1+X1 in flight.
  float4 xa0 = *(const float4*)(X + xo0), xa1 = *(const float4*)(X + xo0 + 4);
  float4 xb0 = *(const float4*)(X + xo1), xb1 = *(const float4*)(X + xo1 + 4);
  gl16(srcB0, &Bl[0][dB0o]);
  gl16(srcB1, &Bl[0][dB1o]);
  gl16(srcB0 + 32, &Bl[1][dB0o]);
  gl16(srcB1 + 32, &Bl[1][dB1o]);
  __builtin_amdgcn_sched_barrier(0);
  *(bf16x8*)&Al[0][lA0] = cvt8(xa0, xa1);
  *(bf16x8*)&Al[0][lA1] = cvt8(xb0, xb1);
  __builtin_amdgcn_sched_barrier(0);
  xa0 = *(const float4*)(X + xo0 + 32); xa1 = *(const float4*)(X + xo0 + 36);
  xb0 = *(const float4*)(X + xo1 + 32); xb1 = *(const float4*)(X + xo1 + 36);
  asm volatile("s_waitcnt vmcnt(6) lgkmcnt(0)\n\ts_barrier" ::: "memory");

  int brd = 0;   // ring slot holding tile it
  for (int it = 0; it < NSTEP; ++it) {
    const int acur = it & 1, anxt = acur ^ 1;
    const int bwr = (brd == 0) ? 2 : brd - 1;      // (brd+2)%3 <- tile it+2
    const int kn2 = ((it + 2) & SM) << 5;          // wrap: valid addr, unused data

    // B(it+2) two tiles ahead into the ring (full-iteration latency window)
    gl16(srcB0 + kn2, &Bl[bwr][dB0o]);
    gl16(srcB1 + kn2, &Bl[bwr][dB1o]);
    __builtin_amdgcn_sched_barrier(0);
    // A(it+1) cvt+write (compiler waits {B(it+1),X(it+1)} -- both 1 iter old;
    // keeps the just-issued B(it+2) in flight)
    *(bf16x8*)&Al[anxt][lA0] = cvt8(xa0, xa1);
    *(bf16x8*)&Al[anxt][lA1] = cvt8(xb0, xb1);
    __builtin_amdgcn_sched_barrier(0);
    // X(it+2) -> regs
    xa0 = *(const float4*)(X + xo0 + kn2); xa1 = *(const float4*)(X + xo0 + kn2 + 4);
    xb0 = *(const float4*)(X + xo1 + kn2); xb1 = *(const float4*)(X + xo1 + kn2 + 4);

    bf16x8 a[4], b[4];
#pragma unroll
    for (int t = 0; t < 4; t++) a[t] = *(const bf16x8*)&Al[acur][offA[t]];
#pragma unroll
    for (int t = 0; t < 4; t++) b[t] = *(const bf16x8*)&Bl[brd][offB[t]];
    asm volatile("s_waitcnt lgkmcnt(0)" ::: "memory");
    __builtin_amdgcn_sched_barrier(0);   // rule #18

#pragma unroll
    for (int tm = 0; tm < 4; tm++)
#pragma unroll
      for (int tn = 0; tn < 4; tn++)
        acc[tm][tn] = __builtin_amdgcn_mfma_f32_16x16x32_bf16(a[tm], b[tn], acc[tm][tn], 0, 0, 0);

    // keep the 6 newest (B(it+2)x2 + X(it+2)x4) in flight across the barrier
    asm volatile("s_waitcnt vmcnt(6)\n\ts_barrier" ::: "memory");
    brd = (brd == 2) ? 0 : brd + 1;
  }

  // C/D layout: col = lane&15, row = quad*4 + reg (verified m89/m91)
#pragma unroll
  for (int tn = 0; tn < 4; tn++) {
    const int col = bn + wn * 64 + tn * 16 + r16;
    const float bias = Bias[col];
#pragma unroll
    for (int tm = 0; tm < 4; tm++) {
      const int row0 = bm + wm * 64 + tm * 16 + quad * 4;
#pragma unroll
      for (int r = 0; r < 4; r++)
        C[(size_t)(row0 + r) * N + col] = f2bf(acc[tm][tn][r] + bias);
    }
  }
}

// ---------------------------------------------------------------------------
// Out projection: X bf16, W bf16, C f32. Depth-2 pipeline: BOTH operands in
// 3-slot rings, gl16 issued 2 tiles ahead; end-of-iter vmcnt(4) drains tile
// it+1 (issued last iter, full window) and keeps tile it+2 in flight.
// LDS 48KB -> 3 blocks/CU.
// ---------------------------------------------------------------------------
__global__ __launch_bounds__(256, 3) void out_gemm_kernel(
    const u16* __restrict__ X, const u16* __restrict__ W,
    const float* __restrict__ Bias, float* __restrict__ C, int N, int K, int M)
{
  __shared__ __attribute__((aligned(16))) u16 Al[3][128 * 32];
  __shared__ __attribute__((aligned(16))) u16 Bl[3][128 * 32];

  const int nwg = (N >> 7) * (M >> 7);
  const int logical = xcd_logical(blockIdx.x, nwg);
  const int nbx = N >> 7;
  const int by = logical / nbx, bx = logical - by * nbx;

  const int tid  = threadIdx.x;
  const int lane = tid & 63;
  const int w    = tid >> 6;
  const int wm = w >> 1, wn = w & 1;
  const int r16 = lane & 15, quad = lane >> 4;
  const int bm = by * 128, bn = bx * 128;

  const int NSTEP = K >> 5;
  const int SM = NSTEP - 1;

  const int s0 = w * 64 + lane, s1 = s0 + 256;
  const int r0 = s0 >> 2, c0 = ((s0 & 3) ^ ((r0 >> 1) & 3)) * 8;
  const int r1 = s1 >> 2, c1 = ((s1 & 3) ^ ((r1 >> 1) & 3)) * 8;

  const u16* srcA0 = X + (size_t)(bm + r0) * K + c0;
  const u16* srcA1 = X + (size_t)(bm + r1) * K + c1;
  const u16* srcB0 = W + (size_t)(bn + r0) * K + c0;
  const u16* srcB1 = W + (size_t)(bn + r1) * K + c1;

  const int dA0o = (w * 64) * 8, dA1o = dA0o + 256 * 8;

  const int swz = (quad ^ ((r16 >> 1) & 3)) * 8;
  int offA[4], offB[4];
#pragma unroll
  for (int t = 0; t < 4; t++) {
    offA[t] = (wm * 64 + t * 16 + r16) * 32 + swz;
    offB[t] = (wn * 64 + t * 16 + r16) * 32 + swz;
  }

  f32x4 acc[4][4];
#pragma unroll
  for (int i = 0; i < 4; i++)
#pragma unroll
    for (int j = 0; j < 4; j++)
      acc[i][j] = f32x4{0.f, 0.f, 0.f, 0.f};

  // prologue: tiles 0,1 -> slots 0,1; drain tile0 only (vmcnt(4))
  gl16(srcA0, &Al[0][dA0o]);
  gl16(srcA1, &Al[0][dA1o]);
  gl16(srcB0, &Bl[0][dA0o]);
  gl16(srcB1, &Bl[0][dA1o]);
  gl16(srcA0 + 32, &Al[1][dA0o]);
  gl16(srcA1 + 32, &Al[1][dA1o]);
  gl16(srcB0 + 32, &Bl[1][dA0o]);
  gl16(srcB1 + 32, &Bl[1][dA1o]);
  asm volatile("s_waitcnt vmcnt(4)\n\ts_barrier" ::: "memory");

  int rd = 0;
  for (int it = 0; it < NSTEP; ++it) {
    const int wr = (rd == 0) ? 2 : rd - 1;     // slot for tile it+2
    const int kn2 = ((it + 2) & SM) << 5;

    gl16(srcA0 + kn2, &Al[wr][dA0o]);
    gl16(srcA1 + kn2, &Al[wr][dA1o]);
    gl16(srcB0 + kn2, &Bl[wr][dA0o]);
    gl16(srcB1 + kn2, &Bl[wr][dA1o]);

    bf16x8 a[4], b[4];
#pragma unroll
    for (int t = 0; t < 4; t++) a[t] = *(const bf16x8*)&Al[rd][offA[t]];
#pragma unroll
    for (int t = 0; t < 4; t++) b[t] = *(const bf16x8*)&Bl[rd][offB[t]];
    asm volatile("s_waitcnt lgkmcnt(0)" ::: "memory");
    __builtin_amdgcn_sched_barrier(0);

#pragma unroll
    for (int tm = 0; tm < 4; tm++)
#pragma unroll
      for (int tn = 0; tn < 4; tn++)
        acc[tm][tn] = __builtin_amdgcn_mfma_f32_16x16x32_bf16(a[tm], b[tn], acc[tm][tn], 0, 0, 0);

    // drain tile(it+1) [issued last iter, 4 oldest]; keep tile(it+2) in flight
    asm volatile("s_waitcnt vmcnt(4)\n\ts_barrier" ::: "memory");
    rd = (rd == 2) ? 0 : rd + 1;
  }

#pragma unroll
  for (int tn = 0; tn < 4; tn++) {
    const int col = bn + wn * 64 + tn * 16 + r16;
    const float bias = Bias[col];
#pragma unroll
    for (int tm = 0; tm < 4; tm++) {
      const int row0 = bm + wm * 64 + tm * 16 + quad * 4;
#pragma unroll
      for (int r = 0; r < 4; r++)
        C[(size_t)(row0 + r) * N + col] = acc[tm][tn][r] + bias;
    }
  }
}

// ---------------------------------------------------------------------------
// Per-token head-mixing attention (reverted to proven (256,4)).
// ---------------------------------------------------------------------------
__global__ __launch_bounds__(256, 4) void attn_heads_kernel(
    const u16* Q, const u16* Km, const u16* V, u16* O)
{
  __shared__ __attribute__((aligned(16))) u16 P[4][16 * LROW];
  __shared__ __attribute__((aligned(16))) u16 VT[4][64 * LROW];

  const int tid = threadIdx.x, lane = tid & 63, w = tid >> 6;
  const int r16 = lane & 15, quad = lane >> 4;
  const size_t base = ((size_t)blockIdx.x * 4 + w) * EMB;

  const bf16x8 aq0 = *(const bf16x8*)&Q[base + r16 * 64 + quad * 8];
  const bf16x8 aq1 = *(const bf16x8*)&Q[base + r16 * 64 + 32 + quad * 8];
  const bf16x8 bk0 = *(const bf16x8*)&Km[base + r16 * 64 + quad * 8];
  const bf16x8 bk1 = *(const bf16x8*)&Km[base + r16 * 64 + 32 + quad * 8];

  const u16x8 v0 = *(const u16x8*)&V[base + lane * 16];
  const u16x8 v1 = *(const u16x8*)&V[base + lane * 16 + 8];
  const u16x8 z8 = {0, 0, 0, 0, 0, 0, 0, 0};
  *(u16x8*)&VT[w][lane * LROW + 16] = z8;
  *(u16x8*)&VT[w][lane * LROW + 24] = z8;
  const int g = lane >> 2, dbase = (lane & 3) * 16;
#pragma unroll
  for (int i = 0; i < 8; i++) {
    VT[w][(dbase + i) * LROW + g]     = v0[i];
    VT[w][(dbase + 8 + i) * LROW + g] = v1[i];
  }

  f32x4 s = f32x4{0.f, 0.f, 0.f, 0.f};
  s = __builtin_amdgcn_mfma_f32_16x16x32_bf16(aq0, bk0, s, 0, 0, 0);
  s = __builtin_amdgcn_mfma_f32_16x16x32_bf16(aq1, bk1, s, 0, 0, 0);

  float p[4];
#pragma unroll
  for (int r = 0; r < 4; r++) {
    float v = s[r] * 0.125f;
    float m = v;
#pragma unroll
    for (int d = 8; d; d >>= 1) m = fmaxf(m, __shfl_xor(m, d, 16));
    float e = __expf(v - m);
    float sum = e;
#pragma unroll
    for (int d = 8; d; d >>= 1) sum += __shfl_xor(sum, d, 16);
    p[r] = e / sum;
  }

#pragma unroll
  for (int r = 0; r < 4; r++) {
    P[w][(quad * 4 + r) * LROW + r16]      = f2bf(p[r]);
    P[w][(quad * 4 + r) * LROW + 16 + r16] = 0;
  }
  __syncthreads();

  const bf16x8 pa = *(const bf16x8*)&P[w][r16 * LROW + quad * 8];

#pragma unroll
  for (int c = 0; c < 4; c++) {
    const bf16x8 bvv = *(const bf16x8*)&VT[w][(c * 16 + r16) * LROW + quad * 8];
    f32x4 o = f32x4{0.f, 0.f, 0.f, 0.f};
    o = __builtin_amdgcn_mfma_f32_16x16x32_bf16(pa, bvv, o, 0, 0, 0);
#pragma unroll
    for (int r = 0; r < 4; r++)
      O[base + (size_t)(quad * 4 + r) * 64 + c * 16 + r16] = f2bf(o[r]);
  }
}

// ---------------------------------------------------------------------------
// Orchestration (unchanged).
// ---------------------------------------------------------------------------
extern "C" void kernel_launch(void* const* d_in, const int* in_sizes, int n_in,
                              void* d_out, int out_size, void* d_ws, size_t ws_size,
                              hipStream_t stream)
{
  const float* values = (const float*)d_in[0];
  const float* keys   = (const float*)d_in[1];
  const float* query  = (const float*)d_in[2];
  const float* Wv = (const float*)d_in[3];
  const float* bv = (const float*)d_in[4];
  const float* Wk = (const float*)d_in[5];
  const float* bk = (const float*)d_in[6];
  const float* Wq = (const float*)d_in[7];
  const float* bq = (const float*)d_in[8];
  const float* Wo = (const float*)d_in[9];
  const float* bo = (const float*)d_in[10];

  const int M = in_sizes[0] / EMB;   // 8192 tokens
  const int N = EMB, K = EMB;

  u16* q    = (u16*)d_ws;
  u16* kbuf = q + (size_t)M * EMB;
  u16* v    = (u16*)d_out;
  u16* wb   = v + (size_t)M * EMB;
  u16* ao   = q;

  const size_t base_ws = (size_t)2 * M * EMB * sizeof(u16);
  const bool wo_in_ws = ws_size >= base_ws + (size_t)EMB * EMB * sizeof(u16);
  u16* wob = wo_in_ws ? kbuf + (size_t)M * EMB : kbuf;

  dim3 blk(256, 1, 1);
  dim3 cwg(EMB * EMB / 8 / 256, wo_in_ws ? 4 : 3, 1);

  hipLaunchKernelGGL(cvtw_kernel, cwg, blk, 0, stream,
                     Wv, wb, Wk, wb + EMB * EMB, Wq, wb + 2 * EMB * EMB, Wo, wob);
  hipLaunchKernelGGL(qkv_fused_kernel, dim3((N / 128) * (M / 128) * 3, 1, 1), blk, 0, stream,
                     values, keys, query, wb, bv, bk, bq, v, kbuf, q, N, K, M);
  hipLaunchKernelGGL(attn_heads_kernel, dim3(M / 4, 1, 1), blk, 0, stream,
                     q, kbuf, v, ao);
  if (!wo_in_ws)
    hipLaunchKernelGGL(cvtw_kernel, dim3(EMB * EMB / 8 / 256, 1, 1), blk, 0, stream,
                       Wo, wob, (const float*)nullptr, (u16*)nullptr,
                       (const float*)nullptr, (u16*)nullptr,
                       (const float*)nullptr, (u16*)nullptr);
  hipLaunchKernelGGL(out_gemm_kernel, dim3((N / 128) * (M / 128), 1, 1), blk, 0, stream,
                     ao, wob, bo, (float*)d_out, N, K, M);
}

// Round 8
// 267.349 us; speedup vs baseline: 3.3136x; 1.0103x over previous
//
#include <hip/hip_runtime.h>
#include <stdint.h>

#define EMB 1024

typedef unsigned short u16;
typedef unsigned int u32;
typedef __attribute__((ext_vector_type(8))) unsigned short u16x8;
typedef __attribute__((ext_vector_type(8))) __bf16 bf16x8;
typedef __attribute__((ext_vector_type(4))) float f32x4;

__device__ __forceinline__ u16 f2bf(float f) {
  union { float f; uint32_t u; } x; x.f = f;
  uint32_t u = x.u;
  u += 0x7fff + ((u >> 16) & 1u);   // round-to-nearest-even
  return (u16)(u >> 16);
}

// 8x f32 -> bf16x8 via native casts (v_cvt_pk_bf16_f32).
__device__ __forceinline__ bf16x8 cvt8(float4 a, float4 b) {
  bf16x8 r;
  r[0] = (__bf16)a.x; r[1] = (__bf16)a.y; r[2] = (__bf16)a.z; r[3] = (__bf16)a.w;
  r[4] = (__bf16)b.x; r[5] = (__bf16)b.y; r[6] = (__bf16)b.z; r[7] = (__bf16)b.w;
  return r;
}

// Async global->LDS, 16B per lane. LDS dest is wave-uniform base + lane*16.
__device__ __forceinline__ void gl16(const u16* g, u16* l) {
  __builtin_amdgcn_global_load_lds(
      (const __attribute__((address_space(1))) void*)g,
      (__attribute__((address_space(3))) void*)l, 16, 0, 0);
}

// XCD-chunked block swizzle (m157; requires nwg % 8 == 0 -- 1536/512 both ok).
__device__ __forceinline__ int xcd_logical(int orig, int nwg) {
  return (orig & 7) * (nwg >> 3) + (orig >> 3);
}

// ---------------------------------------------------------------------------
// Weight cvt: y-indexed (src,dst) pairs, each exactly EMB*EMB elements.
// ---------------------------------------------------------------------------
__global__ __launch_bounds__(256) void cvtw_kernel(
    const float* __restrict__ s0, u16* __restrict__ d0,
    const float* __restrict__ s1, u16* __restrict__ d1,
    const float* __restrict__ s2, u16* __restrict__ d2,
    const float* __restrict__ s3, u16* __restrict__ d3)
{
  const float* s; u16* d;
  switch (blockIdx.y) {
    case 0:  s = s0; d = d0; break;
    case 1:  s = s1; d = d1; break;
    case 2:  s = s2; d = d2; break;
    default: s = s3; d = d3; break;
  }
  const size_t i = (size_t)blockIdx.x * 256 + threadIdx.x;
  const float4* f = (const float4*)(s + i * 8);
  const float4 lo = f[0], hi = f[1];
  *(bf16x8*)(d + i * 8) = cvt8(lo, hi);
}

// ---------------------------------------------------------------------------
// Fused QKV projection (UNCHANGED from round 7: depth-2 W ring, 109us,
// MfmaUtil 19 -- frozen this round to isolate the attn delta).
// ---------------------------------------------------------------------------
__global__ __launch_bounds__(256, 3) void qkv_fused_kernel(
    const float* __restrict__ Vx, const float* __restrict__ Kx,
    const float* __restrict__ Qx, const u16* __restrict__ Wb,
    const float* __restrict__ Bv, const float* __restrict__ Bk,
    const float* __restrict__ Bq,
    u16* __restrict__ cv, u16* __restrict__ ck, u16* __restrict__ cq,
    int N, int K, int M)
{
  __shared__ __attribute__((aligned(16))) u16 Al[2][128 * 32];
  __shared__ __attribute__((aligned(16))) u16 Bl[3][128 * 32];

  const int nwg = (N >> 7) * (M >> 7) * 3;
  const int logical = xcd_logical(blockIdx.x, nwg);
  const int per_z = (N >> 7) * (M >> 7);
  const int z = logical / per_z;
  const int rem = logical - z * per_z;
  const int nbx = N >> 7;
  const int by = rem / nbx, bx = rem - by * nbx;

  const float* X; const u16* W; const float* Bias; u16* C;
  switch (z) {
    case 0:  X = Vx; W = Wb;                   Bias = Bv; C = cv; break;
    case 1:  X = Kx; W = Wb + EMB * EMB;       Bias = Bk; C = ck; break;
    default: X = Qx; W = Wb + 2 * EMB * EMB;   Bias = Bq; C = cq; break;
  }

  const int tid  = threadIdx.x;
  const int lane = tid & 63;
  const int w    = tid >> 6;
  const int wm = w >> 1, wn = w & 1;
  const int r16 = lane & 15, quad = lane >> 4;
  const int bm = by * 128, bn = bx * 128;

  const int NSTEP = K >> 5;   // 32
  const int SM = NSTEP - 1;

  const int s0 = tid, s1 = tid + 256;
  const int r0 = s0 >> 2, c0 = s0 & 3;
  const int r1 = s1 >> 2, c1 = s1 & 3;
  const int lA0 = r0 * 32 + ((c0 ^ ((r0 >> 1) & 3)) * 8);
  const int lA1 = r1 * 32 + ((c1 ^ ((r1 >> 1) & 3)) * 8);
  const size_t xo0 = (size_t)(bm + r0) * K + c0 * 8;
  const size_t xo1 = (size_t)(bm + r1) * K + c1 * 8;

  const int bs0 = w * 64 + lane, bs1 = bs0 + 256;
  const int br0 = bs0 >> 2, bc0 = ((bs0 & 3) ^ ((br0 >> 1) & 3)) * 8;
  const int br1 = bs1 >> 2, bc1 = ((bs1 & 3) ^ ((br1 >> 1) & 3)) * 8;
  const u16* srcB0 = W + (size_t)(bn + br0) * K + bc0;
  const u16* srcB1 = W + (size_t)(bn + br1) * K + bc1;
  const int dB0o = (w * 64) * 8, dB1o = dB0o + 256 * 8;

  const int swz = (quad ^ ((r16 >> 1) & 3)) * 8;
  int offA[4], offB[4];
#pragma unroll
  for (int t = 0; t < 4; t++) {
    offA[t] = (wm * 64 + t * 16 + r16) * 32 + swz;
    offB[t] = (wn * 64 + t * 16 + r16) * 32 + swz;
  }

  f32x4 acc[4][4];
#pragma unroll
  for (int i = 0; i < 4; i++)
#pragma unroll
    for (int j = 0; j < 4; j++)
      acc[i][j] = f32x4{0.f, 0.f, 0.f, 0.f};

  float4 xa0 = *(const float4*)(X + xo0), xa1 = *(const float4*)(X + xo0 + 4);
  float4 xb0 = *(const float4*)(X + xo1), xb1 = *(const float4*)(X + xo1 + 4);
  gl16(srcB0, &Bl[0][dB0o]);
  gl16(srcB1, &Bl[0][dB1o]);
  gl16(srcB0 + 32, &Bl[1][dB0o]);
  gl16(srcB1 + 32, &Bl[1][dB1o]);
  __builtin_amdgcn_sched_barrier(0);
  *(bf16x8*)&Al[0][lA0] = cvt8(xa0, xa1);
  *(bf16x8*)&Al[0][lA1] = cvt8(xb0, xb1);
  __builtin_amdgcn_sched_barrier(0);
  xa0 = *(const float4*)(X + xo0 + 32); xa1 = *(const float4*)(X + xo0 + 36);
  xb0 = *(const float4*)(X + xo1 + 32); xb1 = *(const float4*)(X + xo1 + 36);
  asm volatile("s_waitcnt vmcnt(6) lgkmcnt(0)\n\ts_barrier" ::: "memory");

  int brd = 0;
  for (int it = 0; it < NSTEP; ++it) {
    const int acur = it & 1, anxt = acur ^ 1;
    const int bwr = (brd == 0) ? 2 : brd - 1;
    const int kn2 = ((it + 2) & SM) << 5;

    gl16(srcB0 + kn2, &Bl[bwr][dB0o]);
    gl16(srcB1 + kn2, &Bl[bwr][dB1o]);
    __builtin_amdgcn_sched_barrier(0);
    *(bf16x8*)&Al[anxt][lA0] = cvt8(xa0, xa1);
    *(bf16x8*)&Al[anxt][lA1] = cvt8(xb0, xb1);
    __builtin_amdgcn_sched_barrier(0);
    xa0 = *(const float4*)(X + xo0 + kn2); xa1 = *(const float4*)(X + xo0 + kn2 + 4);
    xb0 = *(const float4*)(X + xo1 + kn2); xb1 = *(const float4*)(X + xo1 + kn2 + 4);

    bf16x8 a[4], b[4];
#pragma unroll
    for (int t = 0; t < 4; t++) a[t] = *(const bf16x8*)&Al[acur][offA[t]];
#pragma unroll
    for (int t = 0; t < 4; t++) b[t] = *(const bf16x8*)&Bl[brd][offB[t]];
    asm volatile("s_waitcnt lgkmcnt(0)" ::: "memory");
    __builtin_amdgcn_sched_barrier(0);

#pragma unroll
    for (int tm = 0; tm < 4; tm++)
#pragma unroll
      for (int tn = 0; tn < 4; tn++)
        acc[tm][tn] = __builtin_amdgcn_mfma_f32_16x16x32_bf16(a[tm], b[tn], acc[tm][tn], 0, 0, 0);

    asm volatile("s_waitcnt vmcnt(6)\n\ts_barrier" ::: "memory");
    brd = (brd == 2) ? 0 : brd + 1;
  }

#pragma unroll
  for (int tn = 0; tn < 4; tn++) {
    const int col = bn + wn * 64 + tn * 16 + r16;
    const float bias = Bias[col];
#pragma unroll
    for (int tm = 0; tm < 4; tm++) {
      const int row0 = bm + wm * 64 + tm * 16 + quad * 4;
#pragma unroll
      for (int r = 0; r < 4; r++)
        C[(size_t)(row0 + r) * N + col] = f2bf(acc[tm][tn][r] + bias);
    }
  }
}

// ---------------------------------------------------------------------------
// Out projection (UNCHANGED from round 7: depth-2 rings both operands).
// ---------------------------------------------------------------------------
__global__ __launch_bounds__(256, 3) void out_gemm_kernel(
    const u16* __restrict__ X, const u16* __restrict__ W,
    const float* __restrict__ Bias, float* __restrict__ C, int N, int K, int M)
{
  __shared__ __attribute__((aligned(16))) u16 Al[3][128 * 32];
  __shared__ __attribute__((aligned(16))) u16 Bl[3][128 * 32];

  const int nwg = (N >> 7) * (M >> 7);
  const int logical = xcd_logical(blockIdx.x, nwg);
  const int nbx = N >> 7;
  const int by = logical / nbx, bx = logical - by * nbx;

  const int tid  = threadIdx.x;
  const int lane = tid & 63;
  const int w    = tid >> 6;
  const int wm = w >> 1, wn = w & 1;
  const int r16 = lane & 15, quad = lane >> 4;
  const int bm = by * 128, bn = bx * 128;

  const int NSTEP = K >> 5;
  const int SM = NSTEP - 1;

  const int s0 = w * 64 + lane, s1 = s0 + 256;
  const int r0 = s0 >> 2, c0 = ((s0 & 3) ^ ((r0 >> 1) & 3)) * 8;
  const int r1 = s1 >> 2, c1 = ((s1 & 3) ^ ((r1 >> 1) & 3)) * 8;

  const u16* srcA0 = X + (size_t)(bm + r0) * K + c0;
  const u16* srcA1 = X + (size_t)(bm + r1) * K + c1;
  const u16* srcB0 = W + (size_t)(bn + r0) * K + c0;
  const u16* srcB1 = W + (size_t)(bn + r1) * K + c1;

  const int dA0o = (w * 64) * 8, dA1o = dA0o + 256 * 8;

  const int swz = (quad ^ ((r16 >> 1) & 3)) * 8;
  int offA[4], offB[4];
#pragma unroll
  for (int t = 0; t < 4; t++) {
    offA[t] = (wm * 64 + t * 16 + r16) * 32 + swz;
    offB[t] = (wn * 64 + t * 16 + r16) * 32 + swz;
  }

  f32x4 acc[4][4];
#pragma unroll
  for (int i = 0; i < 4; i++)
#pragma unroll
    for (int j = 0; j < 4; j++)
      acc[i][j] = f32x4{0.f, 0.f, 0.f, 0.f};

  gl16(srcA0, &Al[0][dA0o]);
  gl16(srcA1, &Al[0][dA1o]);
  gl16(srcB0, &Bl[0][dA0o]);
  gl16(srcB1, &Bl[0][dA1o]);
  gl16(srcA0 + 32, &Al[1][dA0o]);
  gl16(srcA1 + 32, &Al[1][dA1o]);
  gl16(srcB0 + 32, &Bl[1][dA0o]);
  gl16(srcB1 + 32, &Bl[1][dA1o]);
  asm volatile("s_waitcnt vmcnt(4)\n\ts_barrier" ::: "memory");

  int rd = 0;
  for (int it = 0; it < NSTEP; ++it) {
    const int wr = (rd == 0) ? 2 : rd - 1;
    const int kn2 = ((it + 2) & SM) << 5;

    gl16(srcA0 + kn2, &Al[wr][dA0o]);
    gl16(srcA1 + kn2, &Al[wr][dA1o]);
    gl16(srcB0 + kn2, &Bl[wr][dA0o]);
    gl16(srcB1 + kn2, &Bl[wr][dA1o]);

    bf16x8 a[4], b[4];
#pragma unroll
    for (int t = 0; t < 4; t++) a[t] = *(const bf16x8*)&Al[rd][offA[t]];
#pragma unroll
    for (int t = 0; t < 4; t++) b[t] = *(const bf16x8*)&Bl[rd][offB[t]];
    asm volatile("s_waitcnt lgkmcnt(0)" ::: "memory");
    __builtin_amdgcn_sched_barrier(0);

#pragma unroll
    for (int tm = 0; tm < 4; tm++)
#pragma unroll
      for (int tn = 0; tn < 4; tn++)
        acc[tm][tn] = __builtin_amdgcn_mfma_f32_16x16x32_bf16(a[tm], b[tn], acc[tm][tn], 0, 0, 0);

    asm volatile("s_waitcnt vmcnt(4)\n\ts_barrier" ::: "memory");
    rd = (rd == 2) ? 0 : rd + 1;
  }

#pragma unroll
  for (int tn = 0; tn < 4; tn++) {
    const int col = bn + wn * 64 + tn * 16 + r16;
    const float bias = Bias[col];
#pragma unroll
    for (int tm = 0; tm < 4; tm++) {
      const int row0 = bm + wm * 64 + tm * 16 + quad * 4;
#pragma unroll
      for (int r = 0; r < 4; r++)
        C[(size_t)(row0 + r) * N + col] = acc[tm][tn][r] + bias;
    }
  }
}

// ---------------------------------------------------------------------------
// Attention, REWRITTEN: zero LDS, zero barriers -- fully independent waves.
//   * Swapped QK^T: s = mfma(K,Q) -> s[r] = S[h=r16][g=quad*4+r]; softmax
//     over g needs only 2x shfl_xor(16,32) per reduction (was 32 shfls).
//   * P(C-layout) -> A-frag with 4 shfls (quads 2,3 = the K=16..31 zero pad
//     of the 16x16x32 MFMA). No LDS round-trip.
//   * V consumed directly as B-frag via transposed scalar loads
//     V[g=quad*8+j][d=c*16+r16] (quads 0,1 only; each element read exactly
//     once). Issued FIRST so HBM latency hides under QK^T + softmax.
//   * launch_bounds(256,5): 102-reg cap, est ~60 used (round-6 spill lesson).
// ---------------------------------------------------------------------------
__global__ __launch_bounds__(256, 5) void attn_heads_kernel(
    const u16* __restrict__ Q, const u16* __restrict__ Km,
    const u16* __restrict__ V, u16* __restrict__ O)
{
  const int tid = threadIdx.x, lane = tid & 63, w = tid >> 6;
  const int r16 = lane & 15, quad = lane >> 4;
  const size_t base = ((size_t)blockIdx.x * 4 + w) * EMB;

  // ---- V B-frag loads first (latency hides under QK^T + softmax) ----
  u16 vb[4][8];
  const bool vload = quad < 2;
#pragma unroll
  for (int c = 0; c < 4; c++)
#pragma unroll
    for (int j = 0; j < 8; j++)
      vb[c][j] = vload ? V[base + (quad * 8 + j) * 64 + c * 16 + r16] : (u16)0;

  // ---- QK^T swapped: A=K rows(g), B=Q rows(h) ----
  const bf16x8 ak0 = *(const bf16x8*)&Km[base + r16 * 64 + quad * 8];
  const bf16x8 ak1 = *(const bf16x8*)&Km[base + r16 * 64 + 32 + quad * 8];
  const bf16x8 bq0 = *(const bf16x8*)&Q[base + r16 * 64 + quad * 8];
  const bf16x8 bq1 = *(const bf16x8*)&Q[base + r16 * 64 + 32 + quad * 8];

  f32x4 s = f32x4{0.f, 0.f, 0.f, 0.f};
  s = __builtin_amdgcn_mfma_f32_16x16x32_bf16(ak0, bq0, s, 0, 0, 0);
  s = __builtin_amdgcn_mfma_f32_16x16x32_bf16(ak1, bq1, s, 0, 0, 0);
  // s[r] = S[h=r16][g=quad*4+r]

  // ---- softmax over g (spans {quad} x {r}) for column h=r16 ----
  float sv[4];
#pragma unroll
  for (int r = 0; r < 4; r++) sv[r] = s[r] * 0.125f;   // 1/sqrt(64)
  float m = fmaxf(fmaxf(sv[0], sv[1]), fmaxf(sv[2], sv[3]));
  m = fmaxf(m, __shfl_xor(m, 16));
  m = fmaxf(m, __shfl_xor(m, 32));
  float e[4];
  float sum = 0.f;
#pragma unroll
  for (int r = 0; r < 4; r++) { e[r] = __expf(sv[r] - m); sum += e[r]; }
  sum += __shfl_xor(sum, 16);
  sum += __shfl_xor(sum, 32);
  const float rs = 1.0f / sum;

  // pack p into bf16 pairs: wlo={p0,p1}, whi={p2,p3}  (g = quad*4 + {0..3})
  union { __bf16 h[2]; u32 u; } wlo, whi;
  wlo.h[0] = (__bf16)(e[0] * rs); wlo.h[1] = (__bf16)(e[1] * rs);
  whi.h[0] = (__bf16)(e[2] * rs); whi.h[1] = (__bf16)(e[3] * rs);

  // ---- P -> A-frag (A[h=r16][k=quad*8+j]; k>=16 zero) via 4 shfls ----
  const int src0 = r16 + quad * 32;   // source quad' = 2*quad   (valid quad<2)
  const int src1 = src0 + 16;         // source quad' = 2*quad+1
  u32 a0 = (u32)__shfl((int)wlo.u, src0, 64);
  u32 a1 = (u32)__shfl((int)whi.u, src0, 64);
  u32 a2 = (u32)__shfl((int)wlo.u, src1, 64);
  u32 a3 = (u32)__shfl((int)whi.u, src1, 64);
  if (quad >= 2) { a0 = 0; a1 = 0; a2 = 0; a3 = 0; }
  union { u32 u[4]; bf16x8 v; } pa;
  pa.u[0] = a0; pa.u[1] = a1; pa.u[2] = a2; pa.u[3] = a3;

  // ---- PV: O[h][d] = sum_g P[h][g] V[g][d], 4 chunks of 16 d ----
#pragma unroll
  for (int c = 0; c < 4; c++) {
    union { u16 s[8]; bf16x8 v; } vbv;
#pragma unroll
    for (int j = 0; j < 8; j++) vbv.s[j] = vb[c][j];
    f32x4 o = f32x4{0.f, 0.f, 0.f, 0.f};
    o = __builtin_amdgcn_mfma_f32_16x16x32_bf16(pa.v, vbv.v, o, 0, 0, 0);
#pragma unroll
    for (int r = 0; r < 4; r++)
      O[base + (size_t)(quad * 4 + r) * 64 + c * 16 + r16] = f2bf(o[r]);
  }
}

// ---------------------------------------------------------------------------
// Orchestration (unchanged).
// ---------------------------------------------------------------------------
extern "C" void kernel_launch(void* const* d_in, const int* in_sizes, int n_in,
                              void* d_out, int out_size, void* d_ws, size_t ws_size,
                              hipStream_t stream)
{
  const float* values = (const float*)d_in[0];
  const float* keys   = (const float*)d_in[1];
  const float* query  = (const float*)d_in[2];
  const float* Wv = (const float*)d_in[3];
  const float* bv = (const float*)d_in[4];
  const float* Wk = (const float*)d_in[5];
  const float* bk = (const float*)d_in[6];
  const float* Wq = (const float*)d_in[7];
  const float* bq = (const float*)d_in[8];
  const float* Wo = (const float*)d_in[9];
  const float* bo = (const float*)d_in[10];

  const int M = in_sizes[0] / EMB;   // 8192 tokens
  const int N = EMB, K = EMB;

  u16* q    = (u16*)d_ws;
  u16* kbuf = q + (size_t)M * EMB;
  u16* v    = (u16*)d_out;
  u16* wb   = v + (size_t)M * EMB;
  u16* ao   = q;

  const size_t base_ws = (size_t)2 * M * EMB * sizeof(u16);
  const bool wo_in_ws = ws_size >= base_ws + (size_t)EMB * EMB * sizeof(u16);
  u16* wob = wo_in_ws ? kbuf + (size_t)M * EMB : kbuf;

  dim3 blk(256, 1, 1);
  dim3 cwg(EMB * EMB / 8 / 256, wo_in_ws ? 4 : 3, 1);

  hipLaunchKernelGGL(cvtw_kernel, cwg, blk, 0, stream,
                     Wv, wb, Wk, wb + EMB * EMB, Wq, wb + 2 * EMB * EMB, Wo, wob);
  hipLaunchKernelGGL(qkv_fused_kernel, dim3((N / 128) * (M / 128) * 3, 1, 1), blk, 0, stream,
                     values, keys, query, wb, bv, bk, bq, v, kbuf, q, N, K, M);
  hipLaunchKernelGGL(attn_heads_kernel, dim3(M / 4, 1, 1), blk, 0, stream,
                     q, kbuf, v, ao);
  if (!wo_in_ws)
    hipLaunchKernelGGL(cvtw_kernel, dim3(EMB * EMB / 8 / 256, 1, 1), blk, 0, stream,
                       Wo, wob, (const float*)nullptr, (u16*)nullptr,
                       (const float*)nullptr, (u16*)nullptr,
                       (const float*)nullptr, (u16*)nullptr);
  hipLaunchKernelGGL(out_gemm_kernel, dim3((N / 128) * (M / 128), 1, 1), blk, 0, stream,
                     ao, wob, bo, (float*)d_out, N, K, M);
}